// Round 4
// baseline (200.274 us; speedup 1.0000x reference)
//
#include <hip/hip_runtime.h>
#include <hip/hip_cooperative_groups.h>
#include <math.h>

namespace cg = cooperative_groups;

#define NUM_GRAPHS 48
#define F 128
#define MB 16          // atoms per MLP block-tile
#define R 8            // pair blocks per graph
#define NPB (NUM_GRAPHS * R)
#define CHUNK 512      // atoms staged per LDS chunk in pair phase

__device__ __forceinline__ float softplus_f(float x) {
    return fmaxf(x, 0.0f) + log1pf(expf(-fabsf(x)));
}
__device__ __forceinline__ float silu_f(float x) {
    return x / (1.0f + expf(-x));
}

// Single cooperative kernel:
//  Phase A: fused dual-head MLP (weight-coalesced) + block-0 segment scan
//  grid.sync()
//  Phase B: LDS-staged intra-segment pair sweep -> per-block partials
//  grid.sync()
//  Phase C: block 0 reduces partials -> out[0]
__global__ __launch_bounds__(256) void fused_kernel(
    const float* __restrict__ h0,
    const float* __restrict__ qW1, const float* __restrict__ qb1,
    const float* __restrict__ qW2,
    const float* __restrict__ vW1, const float* __restrict__ vb1,
    const float* __restrict__ vW2, const float* __restrict__ vb2,
    const float* __restrict__ pos, const float* __restrict__ sigma_p,
    const int* __restrict__ batch,
    int* __restrict__ seg, float* __restrict__ part,
    float* __restrict__ q_raw, float* __restrict__ c6s, float* __restrict__ rv3,
    float* __restrict__ out, int N)
{
    cg::grid_group grid = cg::this_grid();

    __shared__ float h0s[MB][F];
    __shared__ float red[4][8][3];
    __shared__ float xs[CHUNK], ys[CHUNK], zs[CHUNK];
    __shared__ float qs[CHUNK], ss[CHUNK], r3[CHUNK];
    __shared__ float wred[4];

    const int tid = threadIdx.x;
    const int bid = blockIdx.x;

    // ---------------- Phase A: MLP + seg scan ----------------
    {
        const int a0 = bid * MB;

        if (bid == 0) {  // segment boundaries of sorted batch
            for (int i = tid; i < N; i += 256) {
                int b = batch[i];
                int prev = (i == 0) ? -1 : batch[i - 1];
                for (int g = prev + 1; g <= b; ++g) seg[g] = i;
                if (i == N - 1) {
                    for (int g = b + 1; g <= NUM_GRAPHS; ++g) seg[g] = N;
                }
            }
        }

        if (a0 < N) {
            // stage 16 atom rows (8 KB), coalesced float4
            for (int idx = tid; idx < MB * (F / 4); idx += 256) {
                int a = idx >> 5;
                int kq = idx & 31;
                int row = a0 + a;
                float4 v = make_float4(0.f, 0.f, 0.f, 0.f);
                if (row < N) v = ((const float4*)(h0 + (size_t)row * F))[kq];
                ((float4*)&h0s[a][0])[kq] = v;
            }
            __syncthreads();

            const int j  = tid & 127;
            const int g2 = tid >> 7;

            float accq[8], accv[8];
            const float qb = qb1[j], vb = vb1[j];
            #pragma unroll
            for (int a = 0; a < 8; ++a) { accq[a] = qb; accv[a] = vb; }

            const float* __restrict__ qc = qW1 + j;
            const float* __restrict__ vc = vW1 + j;

            float wq[4], wv[4];
            #pragma unroll
            for (int u = 0; u < 4; ++u) {
                wq[u] = qc[(size_t)u * F];
                wv[u] = vc[(size_t)u * F];
            }

            #pragma unroll 2
            for (int k4 = 0; k4 < F / 4; ++k4) {
                int kn = (k4 < F / 4 - 1) ? (k4 + 1) : k4;
                float nq[4], nv[4];
                #pragma unroll
                for (int u = 0; u < 4; ++u) {
                    nq[u] = qc[(size_t)(kn * 4 + u) * F];
                    nv[u] = vc[(size_t)(kn * 4 + u) * F];
                }
                #pragma unroll
                for (int a = 0; a < 8; ++a) {
                    float4 hv = ((const float4*)&h0s[g2 * 8 + a][0])[k4];
                    float tq = accq[a];
                    tq = fmaf(hv.x, wq[0], tq);
                    tq = fmaf(hv.y, wq[1], tq);
                    tq = fmaf(hv.z, wq[2], tq);
                    tq = fmaf(hv.w, wq[3], tq);
                    accq[a] = tq;
                    float tv = accv[a];
                    tv = fmaf(hv.x, wv[0], tv);
                    tv = fmaf(hv.y, wv[1], tv);
                    tv = fmaf(hv.z, wv[2], tv);
                    tv = fmaf(hv.w, wv[3], tv);
                    accv[a] = tv;
                }
                #pragma unroll
                for (int u = 0; u < 4; ++u) { wq[u] = nq[u]; wv[u] = nv[u]; }
            }

            const float w2q = qW2[j];
            const float w20 = vW2[2 * j];
            const float w21 = vW2[2 * j + 1];
            const int wave = tid >> 6;

            #pragma unroll
            for (int a = 0; a < 8; ++a) {
                float pq = silu_f(accq[a]) * w2q;
                float sv = silu_f(accv[a]);
                float p0 = sv * w20;
                float p1 = sv * w21;
                #pragma unroll
                for (int d = 32; d >= 1; d >>= 1) {
                    pq += __shfl_xor(pq, d);
                    p0 += __shfl_xor(p0, d);
                    p1 += __shfl_xor(p1, d);
                }
                if ((tid & 63) == 0) {
                    red[wave][a][0] = pq;
                    red[wave][a][1] = p0;
                    red[wave][a][2] = p1;
                }
            }
            __syncthreads();

            if (tid < MB) {
                int gg = tid >> 3;
                int al = tid & 7;
                int row = a0 + tid;
                if (row < N) {
                    float pq = red[2 * gg][al][0] + red[2 * gg + 1][al][0];
                    float p0 = red[2 * gg][al][1] + red[2 * gg + 1][al][1];
                    float p1 = red[2 * gg][al][2] + red[2 * gg + 1][al][2];
                    q_raw[row] = pq;
                    c6s[row] = sqrtf(softplus_f(p0 + vb2[0]));
                    float r  = softplus_f(p1 + vb2[1]);
                    rv3[row] = r * r * r;
                }
            }
        }
    }

    grid.sync();

    // ---------------- Phase B: pair sweep ----------------
    if (bid < NPB) {
        const int g     = bid / R;
        const int slice = bid % R;
        const int wave  = tid >> 6;
        const int lane  = tid & 63;
        const int s0 = seg[g], s1 = seg[g + 1];
        const int n = s1 - s0;

        float acc = 0.0f;
        if (n > 1) {
            float ms = 0.f;
            for (int i = s0 + lane; i < s1; i += 64) ms += q_raw[i];
            #pragma unroll
            for (int d = 32; d >= 1; d >>= 1) ms += __shfl_xor(ms, d);
            const float mean = ms / (float)n;
            const float inv_ss = 1.0f / (1.41421356f * sigma_p[0]);
            const int wv = slice * 4 + wave;

            for (int c0 = s0; c0 < s1; c0 += CHUNK) {
                const int cn = min(CHUNK, s1 - c0);
                __syncthreads();
                for (int idx = tid; idx < cn; idx += 256) {
                    int a = c0 + idx;
                    xs[idx] = pos[3 * a + 0];
                    ys[idx] = pos[3 * a + 1];
                    zs[idx] = pos[3 * a + 2];
                    qs[idx] = (q_raw[a] - mean) * (0.5f * 14.3996f);
                    ss[idx] = c6s[a] * 0.5f;
                    r3[idx] = rv3[a];
                }
                __syncthreads();

                for (int i = s0 + wv; i < s1; i += 4 * R) {
                    float xi = pos[3 * i + 0], yi = pos[3 * i + 1], zi = pos[3 * i + 2];
                    float qi = q_raw[i] - mean;
                    float si = c6s[i];
                    float ri = rv3[i];
                    for (int jd = lane; jd < cn; jd += 64) {
                        if (c0 + jd == i) continue;
                        float dx = xi - xs[jd];
                        float dy = yi - ys[jd];
                        float dz = zi - zs[jd];
                        float d2 = fmaf(dx, dx, fmaf(dy, dy, dz * dz));
                        float dist = sqrtf(d2 + 1e-8f);
                        float e1 = qi * qs[jd] * erff(dist * inv_ss) / (dist + 1e-8f);
                        float damp = fmaf(d2 * d2, d2, fmaf(ri, r3[jd], 1e-8f));
                        float e2 = si * ss[jd] / damp;
                        acc += e1 - e2;
                    }
                }
            }
        }
        #pragma unroll
        for (int d = 32; d >= 1; d >>= 1) acc += __shfl_xor(acc, d);
        if (n > 1) {
            if (lane == 0) wred[wave] = acc;
            __syncthreads();
            if (tid == 0) part[bid] = wred[0] + wred[1] + wred[2] + wred[3];
        } else if (tid == 0) {
            part[bid] = 0.0f;
        }
    }

    grid.sync();

    // ---------------- Phase C: final reduce ----------------
    if (bid == 0) {
        double s = 0.0;
        for (int i = tid; i < NPB; i += 256) s += (double)part[i];
        #pragma unroll
        for (int d = 32; d >= 1; d >>= 1) s += __shfl_xor(s, d);
        __shared__ double reds[4];
        if ((tid & 63) == 0) reds[tid >> 6] = s;
        __syncthreads();
        if (tid == 0) out[0] = (float)(reds[0] + reds[1] + reds[2] + reds[3]);
    }
}

extern "C" void kernel_launch(void* const* d_in, const int* in_sizes, int n_in,
                              void* d_out, int out_size, void* d_ws, size_t ws_size,
                              hipStream_t stream) {
    const float* h0   = (const float*)d_in[0];
    // d_in[1] = h1 (unused on this path)
    const float* pos  = (const float*)d_in[2];
    const float* qW1  = (const float*)d_in[3];
    const float* qb1  = (const float*)d_in[4];
    const float* qW2  = (const float*)d_in[5];
    const float* sig  = (const float*)d_in[6];
    const float* vW1  = (const float*)d_in[7];
    const float* vb1  = (const float*)d_in[8];
    const float* vW2  = (const float*)d_in[9];
    const float* vb2  = (const float*)d_in[10];
    const int*  batch = (const int*)d_in[11];
    int N = in_sizes[0] / F;   // 6144

    char* ws = (char*)d_ws;
    int*   seg   = (int*)ws;                 // 49 ints (<=256B)
    float* part  = (float*)(ws + 256);       // NPB floats
    float* q_raw = (float*)(ws + 2048);      // N floats
    float* c6s   = q_raw + N;
    float* rv3   = c6s + N;
    float* out   = (float*)d_out;

    int nb = (N + MB - 1) / MB;
    if (nb < NPB) nb = NPB;

    void* args[] = {
        (void*)&h0, (void*)&qW1, (void*)&qb1, (void*)&qW2,
        (void*)&vW1, (void*)&vb1, (void*)&vW2, (void*)&vb2,
        (void*)&pos, (void*)&sig, (void*)&batch,
        (void*)&seg, (void*)&part, (void*)&q_raw, (void*)&c6s, (void*)&rv3,
        (void*)&out, (void*)&N
    };
    hipLaunchCooperativeKernel((const void*)fused_kernel,
                               dim3(nb), dim3(256), args, 0, stream);
}

// Round 5
// 110.926 us; speedup vs baseline: 1.8055x; 1.8055x over previous
//
#include <hip/hip_runtime.h>
#include <math.h>

#define NUM_GRAPHS 48
#define F 128
#define MB 16          // atoms per MLP block
#define R 8            // pair blocks per graph
#define NPB (NUM_GRAPHS * R)
#define CHUNK 512      // atoms staged per LDS chunk in pair kernel

__device__ __forceinline__ float softplus_f(float x) {
    return fmaxf(x, 0.0f) + log1pf(expf(-fabsf(x)));
}
__device__ __forceinline__ float silu_f(float x) {
    return x / (1.0f + expf(-x));
}

// Fused dual-head MLP + (block 0) segment scan + out zero-init.
// Block: 256 threads = 2 groups of 128. Thread (g2 = tid>>7, j = tid&127)
// computes hidden column j for 8 atoms, both heads. Weight reads W1[k][j]
// coalesced across j; h0 from LDS same-address broadcast (conflict-free).
// Epilogue stores q_raw, sqrt(c6), r_vdw^3.
__global__ __launch_bounds__(256) void mlp_kernel(
    const float* __restrict__ h0,
    const float* __restrict__ qW1, const float* __restrict__ qb1,
    const float* __restrict__ qW2,
    const float* __restrict__ vW1, const float* __restrict__ vb1,
    const float* __restrict__ vW2, const float* __restrict__ vb2,
    const int* __restrict__ batch, int* __restrict__ seg,
    float* __restrict__ q_raw, float* __restrict__ c6s, float* __restrict__ rv3,
    float* __restrict__ out, int N)
{
    __shared__ float h0s[MB][F];
    __shared__ float red[4][8][3];
    const int tid = threadIdx.x;
    const int a0 = blockIdx.x * MB;

    if (blockIdx.x == 0) {   // segment boundaries of sorted batch + out init
        if (tid == 0) out[0] = 0.0f;
        for (int i = tid; i < N; i += 256) {
            int b = batch[i];
            int prev = (i == 0) ? -1 : batch[i - 1];
            for (int g = prev + 1; g <= b; ++g) seg[g] = i;
            if (i == N - 1) {
                for (int g = b + 1; g <= NUM_GRAPHS; ++g) seg[g] = N;
            }
        }
    }

    // stage 16 atom rows (8 KB), coalesced float4
    for (int idx = tid; idx < MB * (F / 4); idx += 256) {
        int a = idx >> 5;
        int kq = idx & 31;
        int row = a0 + a;
        float4 v = make_float4(0.f, 0.f, 0.f, 0.f);
        if (row < N) v = ((const float4*)(h0 + (size_t)row * F))[kq];
        ((float4*)&h0s[a][0])[kq] = v;
    }
    __syncthreads();

    const int j  = tid & 127;
    const int g2 = tid >> 7;

    float accq[8], accv[8];
    const float qb = qb1[j], vb = vb1[j];
    #pragma unroll
    for (int a = 0; a < 8; ++a) { accq[a] = qb; accv[a] = vb; }

    const float* __restrict__ qc = qW1 + j;
    const float* __restrict__ vc = vW1 + j;

    // double-buffered weight prefetch
    float wq[4], wv[4];
    #pragma unroll
    for (int u = 0; u < 4; ++u) {
        wq[u] = qc[(size_t)u * F];
        wv[u] = vc[(size_t)u * F];
    }

    #pragma unroll 2
    for (int k4 = 0; k4 < F / 4; ++k4) {
        int kn = (k4 < F / 4 - 1) ? (k4 + 1) : k4;
        float nq[4], nv[4];
        #pragma unroll
        for (int u = 0; u < 4; ++u) {
            nq[u] = qc[(size_t)(kn * 4 + u) * F];
            nv[u] = vc[(size_t)(kn * 4 + u) * F];
        }
        #pragma unroll
        for (int a = 0; a < 8; ++a) {
            float4 hv = ((const float4*)&h0s[g2 * 8 + a][0])[k4];
            float tq = accq[a];
            tq = fmaf(hv.x, wq[0], tq);
            tq = fmaf(hv.y, wq[1], tq);
            tq = fmaf(hv.z, wq[2], tq);
            tq = fmaf(hv.w, wq[3], tq);
            accq[a] = tq;
            float tv = accv[a];
            tv = fmaf(hv.x, wv[0], tv);
            tv = fmaf(hv.y, wv[1], tv);
            tv = fmaf(hv.z, wv[2], tv);
            tv = fmaf(hv.w, wv[3], tv);
            accv[a] = tv;
        }
        #pragma unroll
        for (int u = 0; u < 4; ++u) { wq[u] = nq[u]; wv[u] = nv[u]; }
    }

    const float w2q = qW2[j];
    const float w20 = vW2[2 * j];
    const float w21 = vW2[2 * j + 1];
    const int wave = tid >> 6;

    #pragma unroll
    for (int a = 0; a < 8; ++a) {
        float pq = silu_f(accq[a]) * w2q;
        float sv = silu_f(accv[a]);
        float p0 = sv * w20;
        float p1 = sv * w21;
        #pragma unroll
        for (int d = 32; d >= 1; d >>= 1) {
            pq += __shfl_xor(pq, d);
            p0 += __shfl_xor(p0, d);
            p1 += __shfl_xor(p1, d);
        }
        if ((tid & 63) == 0) {
            red[wave][a][0] = pq;
            red[wave][a][1] = p0;
            red[wave][a][2] = p1;
        }
    }
    __syncthreads();

    if (tid < MB) {
        int g  = tid >> 3;
        int al = tid & 7;
        int row = a0 + tid;
        if (row < N) {
            float pq = red[2 * g][al][0] + red[2 * g + 1][al][0];
            float p0 = red[2 * g][al][1] + red[2 * g + 1][al][1];
            float p1 = red[2 * g][al][2] + red[2 * g + 1][al][2];
            q_raw[row] = pq;
            c6s[row] = sqrtf(softplus_f(p0 + vb2[0]));
            float r  = softplus_f(p1 + vb2[1]);
            rv3[row] = r * r * r;
        }
    }
}

// 256 threads = 4 waves per block, R blocks per graph. Segment staged into
// LDS; inner loop is LDS+VALU only. Block partial -> one atomicAdd to out.
__global__ __launch_bounds__(256) void pair_kernel(
    const float* __restrict__ pos,
    const float* __restrict__ q_raw,
    const float* __restrict__ c6s, const float* __restrict__ rv3,
    const int* __restrict__ seg, const float* __restrict__ sigma_p,
    float* __restrict__ out)
{
    __shared__ float xs[CHUNK], ys[CHUNK], zs[CHUNK];
    __shared__ float qs[CHUNK], ss[CHUNK], r3[CHUNK];
    __shared__ float wred[4];

    const int g     = blockIdx.x / R;
    const int slice = blockIdx.x % R;
    const int tid   = threadIdx.x;
    const int wave  = tid >> 6;
    const int lane  = tid & 63;
    const int s0 = seg[g], s1 = seg[g + 1];
    const int n = s1 - s0;
    if (n <= 1) return;

    float acc = 0.0f;
    {
        // per-wave (redundant) mean of q over segment
        float ms = 0.f;
        for (int i = s0 + lane; i < s1; i += 64) ms += q_raw[i];
        #pragma unroll
        for (int d = 32; d >= 1; d >>= 1) ms += __shfl_xor(ms, d);
        const float mean = ms / (float)n;
        const float inv_ss = 1.0f / (1.41421356f * sigma_p[0]);
        const int wv = slice * 4 + wave;

        for (int c0 = s0; c0 < s1; c0 += CHUNK) {
            const int cn = min(CHUNK, s1 - c0);
            __syncthreads();
            for (int idx = tid; idx < cn; idx += 256) {
                int a = c0 + idx;
                xs[idx] = pos[3 * a + 0];
                ys[idx] = pos[3 * a + 1];
                zs[idx] = pos[3 * a + 2];
                qs[idx] = (q_raw[a] - mean) * (0.5f * 14.3996f);
                ss[idx] = c6s[a] * 0.5f;
                r3[idx] = rv3[a];
            }
            __syncthreads();

            for (int i = s0 + wv; i < s1; i += 4 * R) {
                float xi = pos[3 * i + 0], yi = pos[3 * i + 1], zi = pos[3 * i + 2];
                float qi = q_raw[i] - mean;
                float si = c6s[i];
                float ri = rv3[i];
                for (int jd = lane; jd < cn; jd += 64) {
                    if (c0 + jd == i) continue;
                    float dx = xi - xs[jd];
                    float dy = yi - ys[jd];
                    float dz = zi - zs[jd];
                    float d2 = fmaf(dx, dx, fmaf(dy, dy, dz * dz));
                    float dist = sqrtf(d2 + 1e-8f);
                    float e1 = qi * qs[jd] * erff(dist * inv_ss) / (dist + 1e-8f);
                    float damp = fmaf(d2 * d2, d2, fmaf(ri, r3[jd], 1e-8f));
                    float e2 = si * ss[jd] / damp;
                    acc += e1 - e2;
                }
            }
        }
    }
    #pragma unroll
    for (int d = 32; d >= 1; d >>= 1) acc += __shfl_xor(acc, d);
    if (lane == 0) wred[wave] = acc;
    __syncthreads();
    if (tid == 0) atomicAdd(out, wred[0] + wred[1] + wred[2] + wred[3]);
}

extern "C" void kernel_launch(void* const* d_in, const int* in_sizes, int n_in,
                              void* d_out, int out_size, void* d_ws, size_t ws_size,
                              hipStream_t stream) {
    const float* h0   = (const float*)d_in[0];
    // d_in[1] = h1 (unused on this path)
    const float* pos  = (const float*)d_in[2];
    const float* qW1  = (const float*)d_in[3];
    const float* qb1  = (const float*)d_in[4];
    const float* qW2  = (const float*)d_in[5];
    const float* sig  = (const float*)d_in[6];
    const float* vW1  = (const float*)d_in[7];
    const float* vb1  = (const float*)d_in[8];
    const float* vW2  = (const float*)d_in[9];
    const float* vb2  = (const float*)d_in[10];
    const int*  batch = (const int*)d_in[11];
    const int N = in_sizes[0] / F;   // 6144

    char* ws = (char*)d_ws;
    int*   seg   = (int*)ws;                 // 49 ints
    float* q_raw = (float*)(ws + 1024);      // N floats
    float* c6s   = q_raw + N;
    float* rv3   = c6s + N;
    float* out   = (float*)d_out;

    mlp_kernel<<<(N + MB - 1) / MB, 256, 0, stream>>>(
        h0, qW1, qb1, qW2, vW1, vb1, vW2, vb2, batch, seg, q_raw, c6s, rv3, out, N);
    pair_kernel<<<NPB, 256, 0, stream>>>(pos, q_raw, c6s, rv3, seg, sig, out);
}